// Round 8
// baseline (117.533 us; speedup 1.0000x reference)
//
#include <hip/hip_runtime.h>
#include <hip/hip_bf16.h>

#define HH 128
#define WW 128
#define CI 64
#define CO 64
#define SLS 584    // SL row stride in bf16 elems (576 + 8 pad)
#define HPS 72     // halo pixel stride in bf16 elems (64 + 8 pad, 144B = 9x16B)
#define HALW 18    // halo width: image cols w0-1 .. w0+16

typedef __attribute__((ext_vector_type(8))) short short8;
typedef __attribute__((ext_vector_type(4))) float floatx4;

__device__ __forceinline__ unsigned short f2bf(float f) {
  union { float f; unsigned u; } uu; uu.f = f;
  unsigned r = uu.u + 0x7FFFu + ((uu.u >> 16) & 1u);  // RNE
  return (unsigned short)(r >> 16);
}
__device__ __forceinline__ unsigned pack2bf(float lo, float hi) {
  return (unsigned)f2bf(lo) | ((unsigned)f2bf(hi) << 16);
}
__device__ __forceinline__ float bfl(unsigned u) { return __uint_as_float(u << 16); }
__device__ __forceinline__ float bfh(unsigned u) { return __uint_as_float(u & 0xffff0000u); }

// ---- K1: blocks 0..1023 transcode x (f32 NCHW) -> xTb (bf16 NHWC ch-pairs),
//          32 px per block; blocks 1024..1167 prep Wm/w2/bias2/boff2 ----
__global__ __launch_bounds__(256) void prep_kernel(
    const float* __restrict__ x, unsigned* __restrict__ xTb_u,
    const float* __restrict__ weight, const float* __restrict__ bias,
    const float* __restrict__ gamma, const float* __restrict__ beta,
    const float* __restrict__ mean, const float* __restrict__ var,
    const float* __restrict__ w_off, const float* __restrict__ b_off,
    unsigned short* __restrict__ Wm, unsigned short* __restrict__ w2,
    float* __restrict__ bias2, float* __restrict__ boff2) {
  __shared__ unsigned T2[32 * 33];  // [px][cp] with +1 pad: 4,224 B
  int bid = blockIdx.x;
  int tid = threadIdx.x;
  if (bid < 1024) {
    int b = bid >> 9, h = (bid >> 2) & 127, q = bid & 3;  // 32-px chunk q
    int cp = tid >> 3, wc = tid & 7;  // ch pair (2cp,2cp+1), 4-px chunk wc
    const float* xp = x + (((long)(b * CI + 2 * cp) * HH + h) * WW + q * 32 + wc * 4);
    float4 a0 = *(const float4*)xp;              // ch 2cp
    float4 a1 = *(const float4*)(xp + HH * WW);  // ch 2cp+1
    T2[(wc * 4 + 0) * 33 + cp] = pack2bf(a0.x, a1.x);
    T2[(wc * 4 + 1) * 33 + cp] = pack2bf(a0.y, a1.y);
    T2[(wc * 4 + 2) * 33 + cp] = pack2bf(a0.z, a1.z);
    T2[(wc * 4 + 3) * 33 + cp] = pack2bf(a0.w, a1.w);
    __syncthreads();
    int px = tid >> 3, g = tid & 7;
    const unsigned* src = &T2[px * 33 + g * 4];
    unsigned* dst = xTb_u + ((long)((b * HH + h) * WW + q * 32 + px)) * 32 + g * 4;
    *(uint4*)dst = make_uint4(src[0], src[1], src[2], src[3]);
    return;
  }
  int idx = (bid - 1024) * 256 + tid;
  if (idx < 32) boff2[idx] = (idx < 27) ? b_off[idx] : 0.f;
  if (idx >= CO * 576) return;
  int o = idx / 576, kc = idx - o * 576;
  int k = kc >> 6, c = kc & 63;
  float inv = gamma[o] * rsqrtf(var[o] + 1e-5f);
  Wm[idx] = f2bf(weight[(o * CI + c) * 9 + k] * inv);
  if (kc == 0) bias2[o] = (bias[o] - mean[o]) * inv + beta[o];
  if (o < 27) w2[idx] = f2bf(w_off[o * 576 + c * 9 + k]);
  else if (o < 32) w2[idx] = 0;
}

// ---- K2a: offset pass — halo stage | offset GEMM | fused params -> Pw4/PoI ----
// 16 px/block, 2048 blocks. LDS 12,384 B; register-light -> runs wide.
__global__ __launch_bounds__(256) void off_kernel(
    const unsigned short* __restrict__ xTb,
    const unsigned short* __restrict__ w2, const float* __restrict__ boff2,
    float4* __restrict__ Pw4, int* __restrict__ PoI) {
  __shared__ short hal[3 * HALW * HPS];  // 7,776 B
  __shared__ float omL[2 * 16 * 36];     // 4,608 B

  int bid = blockIdx.x;
  int s = bid & 7;              // XCD slab key
  int n = bid >> 3;             // 0..255
  int b = n >> 7;
  int rem = n & 127;
  int h = s * 16 + (rem >> 3);
  int w0 = (rem & 7) * 16;
  int tid = threadIdx.x, lane = tid & 63, wave = tid >> 6;

  // stage halo rows h-1..h+1, cols w0-1..w0+16, 64 ch (zeros off-image)
#pragma unroll
  for (int it = 0; it < 2; it++) {
    int t = it * 256 + tid;
    if (t < 432) {
      int row = t / 144;
      int r2 = t - row * 144;
      int xi = r2 >> 3, cg = r2 & 7;
      int y = h - 1 + row, xx = w0 - 1 + xi;
      uint4 v = make_uint4(0u, 0u, 0u, 0u);
      if ((unsigned)y < (unsigned)HH && (unsigned)xx < (unsigned)WW)
        v = *(const uint4*)(xTb + (long)((b * HH + y) * WW + xx) * CI + cg * 8);
      *(uint4*)(hal + (row * HALW + xi) * HPS + cg * 8) = v;
    }
  }
  __syncthreads();

  // offset GEMM M=32(27) x N=16 px x K=576; wave = (m16, khalf)
  {
    int r16 = lane & 15, quad = lane >> 4;
    int m16 = wave & 1, kh = wave >> 1;
    floatx4 t0 = {0.f, 0.f, 0.f, 0.f};
    floatx4 t1 = {0.f, 0.f, 0.f, 0.f};
    if (kh == 0) t0 = *(const floatx4*)(boff2 + m16 * 16 + quad * 4);
    const short* ap = (const short*)(w2 + (m16 * 16 + r16) * 576 + kh * 32 + quad * 8);
#pragma unroll
    for (int kk = 0; kk < 9; kk++) {
      int dy = kk / 3, dxk = kk - 3 * dy;
      short8 bfrag = *(const short8*)(hal + (dy * HALW + r16 + dxk) * HPS + kh * 32 + quad * 8);
      short8 afrag = *(const short8*)(ap + kk * 64);
      if (kk & 1)
        t1 = __builtin_amdgcn_mfma_f32_16x16x32_bf16(afrag, bfrag, t1, 0, 0, 0);
      else
        t0 = __builtin_amdgcn_mfma_f32_16x16x32_bf16(afrag, bfrag, t0, 0, 0, 0);
    }
    floatx4 t = t0 + t1;
    *(floatx4*)(omL + kh * 576 + r16 * 36 + m16 * 16 + quad * 4) = t;
  }
  __syncthreads();

  // params: 36 (p,k) tasks per wave for its 4 px; write packed to global
  if (lane < 36) {
    int p_loc = (lane * 7282) >> 16;  // lane/9
    int k = lane - p_loc * 9;
    int p = wave * 4 + p_loc;
    const float* o0 = omL + p * 36;
    const float* o1 = omL + 576 + p * 36;
    float oy = o0[2 * k] + o1[2 * k];
    float ox = o0[2 * k + 1] + o1[2 * k + 1];
    float mm = o0[18 + k] + o1[18 + k];
    float msk = 1.f / (1.f + __expf(-mm));
    int ky = (k * 11) >> 5;  // k/3
    int kx = k - 3 * ky;
    float py = (float)(h - 1 + ky) + oy;
    float pxx = (float)(w0 + p - 1 + kx) + ox;
    float y0f = floorf(py), x0f = floorf(pxx);
    float ly = py - y0f, lx = pxx - x0f;
    int y0 = (int)y0f, x0 = (int)x0f;
    int y1 = y0 + 1, x1 = x0 + 1;
    float lylx = ly * lx;
    bool y0v = (unsigned)y0 < (unsigned)HH, y1v = (unsigned)y1 < (unsigned)HH;
    bool x0v = (unsigned)x0 < (unsigned)WW, x1v = (unsigned)x1 < (unsigned)WW;
    int yc0 = min(max(y0, 0), HH - 1), yc1 = min(max(y1, 0), HH - 1);
    int xc0 = min(max(x0, 0), WW - 1), xc1 = min(max(x1, 0), WW - 1);
    float wx = (y0v && x0v) ? (1.f - ly - lx + lylx) * msk : 0.f;
    float wy = (y0v && x1v) ? (lx - lylx) * msk : 0.f;
    float wz = (y1v && x0v) ? (ly - lylx) * msk : 0.f;
    float ww = (y1v && x1v) ? lylx * msk : 0.f;
    int off00 = (yc0 * WW + xc0) * CI;     // < 2^20
    int dxs = (xc1 - xc0) * CI;            // 0 or 64
    int dys = (yc1 - yc0) * WW * CI;       // 0 or 8192
    int gi = (((b * HH + h) * WW + w0) + p) * 9 + k;
    Pw4[gi] = make_float4(wx, wy, wz, ww);
    PoI[gi] = off00 | ((dxs >> 6) << 20) | ((dys >> 13) << 21);
  }
}

// ---- K2b: gather + main GEMM + BN + ReLU. 16 px/block, 2048 blocks ----
// params->LDS (1 coalesced round) | pipelined 36-tap gather | barrier | GEMM.
// NO occupancy cap: allocator free to keep the gather pipeline in registers.
__global__ __launch_bounds__(256) void gemm_kernel(
    const unsigned short* __restrict__ xTb, const float4* __restrict__ Pw4,
    const int* __restrict__ PoI, const unsigned short* __restrict__ Wm,
    const float* __restrict__ bias2, float* __restrict__ out) {
  __shared__ __hip_bfloat16 SL[16 * SLS];  // 18,688 B
  __shared__ float4 PwL[144];              //  2,304 B
  __shared__ int PoL[144];                 //    576 B

  int bid = blockIdx.x;
  int s = bid & 7;              // XCD slab key
  int n = bid >> 3;             // 0..255
  int b = n >> 7;
  int rem = n & 127;
  int h = s * 16 + (rem >> 3);
  int w0 = (rem & 7) * 16;
  int tid = threadIdx.x, lane = tid & 63, wave = tid >> 6;
  int rowpix = (b * HH + h) * WW + w0;

  if (tid < 144) {
    PwL[tid] = Pw4[rowpix * 9 + tid];
    PoL[tid] = PoI[rowpix * 9 + tid];
  }
  __syncthreads();  // params staged

  // gather: 16 lanes/px, 4 ch/lane, dwordx2 taps; 4-chunk software pipeline
  {
    int cq = lane & 15, pl = lane >> 4;
    int p = wave * 4 + pl;
    int ch = cq * 4;
    const unsigned short* xb = xTb + (long)b * (HH * WW * CI);
    uint2 uA[3][4], uB[2][4], uC[2][4], uD[2][4];

#define LOADK(U, kk)                                  \
    {                                                 \
      int v = PoL[p * 9 + (kk)];                      \
      int o00 = (v & 0xFFFFF) + ch;                   \
      int dxv = (v >> 14) & 64;                       \
      int dyv = (v >> 8) & 8192;                      \
      U[0] = *(const uint2*)(xb + o00);               \
      U[1] = *(const uint2*)(xb + o00 + dxv);         \
      U[2] = *(const uint2*)(xb + o00 + dyv);         \
      U[3] = *(const uint2*)(xb + o00 + dyv + dxv);   \
    }

#define COMBK(U, kk)                                                                          \
    {                                                                                         \
      float4 wv = PwL[p * 9 + (kk)];                                                          \
      float wx = wv.x, wy = wv.y, wz = wv.z, ww = wv.w;                                       \
      float lo0 = bfl(U[0].x) * wx + bfl(U[1].x) * wy + bfl(U[2].x) * wz + bfl(U[3].x) * ww;  \
      float hi0 = bfh(U[0].x) * wx + bfh(U[1].x) * wy + bfh(U[2].x) * wz + bfh(U[3].x) * ww;  \
      float lo1 = bfl(U[0].y) * wx + bfl(U[1].y) * wy + bfl(U[2].y) * wz + bfl(U[3].y) * ww;  \
      float hi1 = bfh(U[0].y) * wx + bfh(U[1].y) * wy + bfh(U[2].y) * wz + bfh(U[3].y) * ww;  \
      unsigned r0, r1;                                                                        \
      asm("v_cvt_pk_bf16_f32 %0, %1, %2" : "=v"(r0) : "v"(lo0), "v"(hi0));                    \
      asm("v_cvt_pk_bf16_f32 %0, %1, %2" : "=v"(r1) : "v"(lo1), "v"(hi1));                    \
      *(uint2*)(&SL[p * SLS + (kk) * 64 + ch]) = make_uint2(r0, r1);                          \
    }

    LOADK(uA[0], 0) LOADK(uA[1], 1) LOADK(uA[2], 2)
    LOADK(uB[0], 3) LOADK(uB[1], 4)
    COMBK(uA[0], 0) COMBK(uA[1], 1) COMBK(uA[2], 2)
    LOADK(uC[0], 5) LOADK(uC[1], 6)
    COMBK(uB[0], 3) COMBK(uB[1], 4)
    LOADK(uD[0], 7) LOADK(uD[1], 8)
    COMBK(uC[0], 5) COMBK(uC[1], 6)
    COMBK(uD[0], 7) COMBK(uD[1], 8)
#undef LOADK
#undef COMBK
  }
  __syncthreads();  // SL complete

  // main GEMM — wave's 16 oc x block's 16 px, K=576; BN bias in C-init, ReLU
  {
    int r16 = lane & 15, quad = lane >> 4;
    floatx4 acc0 = *(const floatx4*)(bias2 + wave * 16 + quad * 4);
    floatx4 acc1 = {0.f, 0.f, 0.f, 0.f};
    const unsigned short* Ap = Wm + (wave * 16 + r16) * 576 + quad * 8;
    const __hip_bfloat16* Sp = &SL[r16 * SLS + quad * 8];
#pragma unroll
    for (int kc0 = 0; kc0 < 576; kc0 += 64) {
      short8 av0 = *(const short8*)(Ap + kc0);
      short8 bv0 = *(const short8*)(Sp + kc0);
      acc0 = __builtin_amdgcn_mfma_f32_16x16x32_bf16(av0, bv0, acc0, 0, 0, 0);
      short8 av1 = *(const short8*)(Ap + kc0 + 32);
      short8 bv1 = *(const short8*)(Sp + kc0 + 32);
      acc1 = __builtin_amdgcn_mfma_f32_16x16x32_bf16(av1, bv1, acc1, 0, 0, 0);
    }
    floatx4 acc = acc0 + acc1;
#pragma unroll
    for (int r = 0; r < 4; r++) {
      int o = wave * 16 + quad * 4 + r;
      out[((b * CO + o) * HH + h) * WW + w0 + r16] = fmaxf(acc[r], 0.f);
    }
  }
}

extern "C" void kernel_launch(void* const* d_in, const int* in_sizes, int n_in,
                              void* d_out, int out_size, void* d_ws, size_t ws_size,
                              hipStream_t stream) {
  const float* x = (const float*)d_in[0];
  const float* w_off = (const float*)d_in[1];
  const float* b_off = (const float*)d_in[2];
  const float* weight = (const float*)d_in[3];
  const float* bias = (const float*)d_in[4];
  const float* gamma = (const float*)d_in[5];
  const float* beta = (const float*)d_in[6];
  const float* run_mean = (const float*)d_in[7];
  const float* run_var = (const float*)d_in[8];
  float* outp = (float*)d_out;

  char* ws = (char*)d_ws;
  unsigned* xTb = (unsigned*)ws;                           // 4,194,304 B (bf16 NHWC)
  unsigned short* Wm = (unsigned short*)(ws + 4194304);    //    73,728 B
  unsigned short* w2 = (unsigned short*)(ws + 4268032);    //    36,864 B
  float* bias2 = (float*)(ws + 4304896);                   //       256 B
  float* boff2 = (float*)(ws + 4305152);                   //       128 B
  float4* Pw4 = (float4*)(ws + 4305280);                   // 4,718,592 B
  int* PoI = (int*)(ws + 9023872);                         // 1,179,648 B

  prep_kernel<<<1168, 256, 0, stream>>>(x, xTb, weight, bias, gamma, beta,
                                        run_mean, run_var, w_off, b_off,
                                        Wm, w2, bias2, boff2);
  off_kernel<<<2048, 256, 0, stream>>>((const unsigned short*)xTb, w2, boff2,
                                       Pw4, PoI);
  gemm_kernel<<<2048, 256, 0, stream>>>((const unsigned short*)xTb, Pw4, PoI,
                                        Wm, bias2, outp);
}

// Round 9
// 110.624 us; speedup vs baseline: 1.0625x; 1.0625x over previous
//
#include <hip/hip_runtime.h>
#include <hip/hip_bf16.h>

#define HH 128
#define WW 128
#define CI 64
#define CO 64
#define SLS 584    // SL row stride in bf16 elems (576 + 8 pad)
#define HPS 72     // halo pixel stride in bf16 elems (64 + 8 pad, 144B = 9x16B)
#define HALW 18    // halo width: image cols w0-1 .. w0+16
#define TS 18688   // per-tile LDS region (bytes)

typedef __attribute__((ext_vector_type(8))) short short8;
typedef __attribute__((ext_vector_type(4))) float floatx4;

__device__ __forceinline__ unsigned short f2bf(float f) {
  union { float f; unsigned u; } uu; uu.f = f;
  unsigned r = uu.u + 0x7FFFu + ((uu.u >> 16) & 1u);  // RNE
  return (unsigned short)(r >> 16);
}
__device__ __forceinline__ unsigned pack2bf(float lo, float hi) {
  return (unsigned)f2bf(lo) | ((unsigned)f2bf(hi) << 16);
}
__device__ __forceinline__ float bfl(unsigned u) { return __uint_as_float(u << 16); }
__device__ __forceinline__ float bfh(unsigned u) { return __uint_as_float(u & 0xffff0000u); }

// ---- K1: blocks 0..1023 transcode x (f32 NCHW) -> xTb (bf16 NHWC ch-pairs),
//          32 px per block; blocks 1024..1167 prep Wm/w2/bias2/boff2 ----
__global__ __launch_bounds__(256) void prep_kernel(
    const float* __restrict__ x, unsigned* __restrict__ xTb_u,
    const float* __restrict__ weight, const float* __restrict__ bias,
    const float* __restrict__ gamma, const float* __restrict__ beta,
    const float* __restrict__ mean, const float* __restrict__ var,
    const float* __restrict__ w_off, const float* __restrict__ b_off,
    unsigned short* __restrict__ Wm, unsigned short* __restrict__ w2,
    float* __restrict__ bias2, float* __restrict__ boff2) {
  __shared__ unsigned T2[32 * 33];  // [px][cp] with +1 pad: 4,224 B
  int bid = blockIdx.x;
  int tid = threadIdx.x;
  if (bid < 1024) {
    int b = bid >> 9, h = (bid >> 2) & 127, q = bid & 3;  // 32-px chunk q
    int cp = tid >> 3, wc = tid & 7;  // ch pair (2cp,2cp+1), 4-px chunk wc
    const float* xp = x + (((long)(b * CI + 2 * cp) * HH + h) * WW + q * 32 + wc * 4);
    float4 a0 = *(const float4*)xp;              // ch 2cp
    float4 a1 = *(const float4*)(xp + HH * WW);  // ch 2cp+1
    T2[(wc * 4 + 0) * 33 + cp] = pack2bf(a0.x, a1.x);
    T2[(wc * 4 + 1) * 33 + cp] = pack2bf(a0.y, a1.y);
    T2[(wc * 4 + 2) * 33 + cp] = pack2bf(a0.z, a1.z);
    T2[(wc * 4 + 3) * 33 + cp] = pack2bf(a0.w, a1.w);
    __syncthreads();
    int px = tid >> 3, g = tid & 7;
    const unsigned* src = &T2[px * 33 + g * 4];
    unsigned* dst = xTb_u + ((long)((b * HH + h) * WW + q * 32 + px)) * 32 + g * 4;
    *(uint4*)dst = make_uint4(src[0], src[1], src[2], src[3]);
    return;
  }
  int idx = (bid - 1024) * 256 + tid;
  if (idx < 32) boff2[idx] = (idx < 27) ? b_off[idx] : 0.f;
  if (idx >= CO * 576) return;
  int o = idx / 576, kc = idx - o * 576;
  int k = kc >> 6, c = kc & 63;
  float inv = gamma[o] * rsqrtf(var[o] + 1e-5f);
  Wm[idx] = f2bf(weight[(o * CI + c) * 9 + k] * inv);
  if (kc == 0) bias2[o] = (bias[o] - mean[o]) * inv + beta[o];
  if (o < 27) w2[idx] = f2bf(w_off[o * 576 + c * 9 + k]);
  else if (o < 32) w2[idx] = 0;
}

// ---- K2: fused DCN, TWO 16-px tiles per block, 1024 blocks (4/CU, one
// generation). Every phase covers both tiles -> half the barriers per pixel,
// 2x independent work next to every latency round (anti-convoy).
// Per-tile LDS region (18,688 B): SL[16][584]; hal aliases rows 0-6;
// omL aliases rows 12-15. Total 37,376 B.
__global__ __launch_bounds__(256, 4) void dcn_kernel(
    const unsigned short* __restrict__ xTb,
    const unsigned short* __restrict__ w2, const float* __restrict__ boff2,
    const unsigned short* __restrict__ Wm, const float* __restrict__ bias2,
    float* __restrict__ out) {
  __shared__ char smem[2 * TS];

  int bid = blockIdx.x;
  int s = bid & 7;              // XCD slab key
  int n = bid >> 3;             // 0..127
  int b = n >> 6;
  int rem = n & 63;
  int h = s * 16 + (rem >> 2);
  int w00 = (rem & 3) * 32;     // tile X at w00, tile Y at w00+16
  int tid = threadIdx.x, lane = tid & 63, wave = tid >> 6;

  // phase 0: stage BOTH halos (864 tasks = 2 x 432), zeros off-image
#pragma unroll
  for (int it = 0; it < 4; it++) {
    int t = it * 256 + tid;
    if (t < 864) {
      int ti = (t >= 432);
      int tt = t - ti * 432;
      int row = tt / 144;
      int r2 = tt - row * 144;
      int xi = r2 >> 3, cg = r2 & 7;
      int y = h - 1 + row, xx = w00 + ti * 16 - 1 + xi;
      uint4 v = make_uint4(0u, 0u, 0u, 0u);
      if ((unsigned)y < (unsigned)HH && (unsigned)xx < (unsigned)WW)
        v = *(const uint4*)(xTb + (long)((b * HH + y) * WW + xx) * CI + cg * 8);
      short* hal = (short*)(smem + ti * TS);
      *(uint4*)(hal + (row * HALW + xi) * HPS + cg * 8) = v;
    }
  }
  __syncthreads();  // A: halos ready

  // phase 1: offset GEMMs, both tiles. wave=(m16,kh), M=32(27) N=16 K=576
  {
    int r16 = lane & 15, quad = lane >> 4;
    int m16 = wave & 1, kh = wave >> 1;
#pragma unroll
    for (int ti = 0; ti < 2; ti++) {
      short* hal = (short*)(smem + ti * TS);
      float* omL = (float*)(smem + ti * TS + 14016);
      floatx4 t0 = {0.f, 0.f, 0.f, 0.f};
      floatx4 t1 = {0.f, 0.f, 0.f, 0.f};
      if (kh == 0) t0 = *(const floatx4*)(boff2 + m16 * 16 + quad * 4);
      const short* ap = (const short*)(w2 + (m16 * 16 + r16) * 576 + kh * 32 + quad * 8);
#pragma unroll
      for (int kk = 0; kk < 9; kk++) {
        int dy = kk / 3, dxk = kk - 3 * dy;
        short8 bfrag = *(const short8*)(hal + (dy * HALW + r16 + dxk) * HPS + kh * 32 + quad * 8);
        short8 afrag = *(const short8*)(ap + kk * 64);
        if (kk & 1)
          t1 = __builtin_amdgcn_mfma_f32_16x16x32_bf16(afrag, bfrag, t1, 0, 0, 0);
        else
          t0 = __builtin_amdgcn_mfma_f32_16x16x32_bf16(afrag, bfrag, t0, 0, 0, 0);
      }
      floatx4 t = t0 + t1;
      // C layout: col=r16=px, row=quad*4+r=oc-in-tile
      *(floatx4*)(omL + kh * 576 + r16 * 36 + m16 * 16 + quad * 4) = t;
    }
  }
  __syncthreads();  // B: omL ready, hal reads done

  // phase 2a: params for both tiles, kept in REGISTERS
  float pwx[2] = {0.f, 0.f}, pwy[2] = {0.f, 0.f}, pwz[2] = {0.f, 0.f}, pww[2] = {0.f, 0.f};
  int pov[2] = {0, 0};
  if (lane < 36) {
    int p_loc = (lane * 7282) >> 16;  // lane/9
    int k = lane - p_loc * 9;
    int p = wave * 4 + p_loc;
    int ky = (k * 11) >> 5;  // k/3
    int kx = k - 3 * ky;
#pragma unroll
    for (int ti = 0; ti < 2; ti++) {
      const float* omL = (const float*)(smem + ti * TS + 14016);
      int w0 = w00 + ti * 16;
      const float* o0 = omL + p * 36;
      const float* o1 = omL + 576 + p * 36;
      float oy = o0[2 * k] + o1[2 * k];
      float ox = o0[2 * k + 1] + o1[2 * k + 1];
      float mm = o0[18 + k] + o1[18 + k];
      float msk = 1.f / (1.f + __expf(-mm));
      float py = (float)(h - 1 + ky) + oy;
      float pxx = (float)(w0 + p - 1 + kx) + ox;
      float y0f = floorf(py), x0f = floorf(pxx);
      float ly = py - y0f, lx = pxx - x0f;
      int y0 = (int)y0f, x0 = (int)x0f;
      int y1 = y0 + 1, x1 = x0 + 1;
      float lylx = ly * lx;
      bool y0v = (unsigned)y0 < (unsigned)HH, y1v = (unsigned)y1 < (unsigned)HH;
      bool x0v = (unsigned)x0 < (unsigned)WW, x1v = (unsigned)x1 < (unsigned)WW;
      int yc0 = min(max(y0, 0), HH - 1), yc1 = min(max(y1, 0), HH - 1);
      int xc0 = min(max(x0, 0), WW - 1), xc1 = min(max(x1, 0), WW - 1);
      pwx[ti] = (y0v && x0v) ? (1.f - ly - lx + lylx) * msk : 0.f;
      pwy[ti] = (y0v && x1v) ? (lx - lylx) * msk : 0.f;
      pwz[ti] = (y1v && x0v) ? (ly - lylx) * msk : 0.f;
      pww[ti] = (y1v && x1v) ? lylx * msk : 0.f;
      int off00 = (yc0 * WW + xc0) * CI;     // < 2^20
      int dxs = (xc1 - xc0) * CI;            // 0 or 64
      int dys = (yc1 - yc0) * WW * CI;       // 0 or 8192
      pov[ti] = off00 | ((dxs >> 6) << 20) | ((dys >> 13) << 21);
    }
  }
  __syncthreads();  // C: omL reads done before SL rows 12-15 are overwritten

  // phase 2b: gathers for both tiles; 4-chunk pipeline per tile, params via shfl
  {
    int cq = lane & 15, pl = lane >> 4;
    int p = wave * 4 + pl;
    int ch = cq * 4;
    const unsigned short* xb = xTb + (long)b * (HH * WW * CI);
    uint2 uA[3][4], uB[2][4], uC[2][4], uD[2][4];

#define LOADK(U, kk)                                  \
    {                                                 \
      int v = __shfl(povt, pl * 9 + (kk));            \
      int o00 = (v & 0xFFFFF) + ch;                   \
      int dxv = (v >> 14) & 64;                       \
      int dyv = (v >> 8) & 8192;                      \
      U[0] = *(const uint2*)(xb + o00);               \
      U[1] = *(const uint2*)(xb + o00 + dxv);         \
      U[2] = *(const uint2*)(xb + o00 + dyv);         \
      U[3] = *(const uint2*)(xb + o00 + dyv + dxv);   \
    }

#define COMBK(U, kk)                                                                          \
    {                                                                                         \
      int src = pl * 9 + (kk);                                                                \
      float wx = __shfl(pwxt, src), wy = __shfl(pwyt, src);                                   \
      float wz = __shfl(pwzt, src), ww = __shfl(pwwt, src);                                   \
      float lo0 = bfl(U[0].x) * wx + bfl(U[1].x) * wy + bfl(U[2].x) * wz + bfl(U[3].x) * ww;  \
      float hi0 = bfh(U[0].x) * wx + bfh(U[1].x) * wy + bfh(U[2].x) * wz + bfh(U[3].x) * ww;  \
      float lo1 = bfl(U[0].y) * wx + bfl(U[1].y) * wy + bfl(U[2].y) * wz + bfl(U[3].y) * ww;  \
      float hi1 = bfh(U[0].y) * wx + bfh(U[1].y) * wy + bfh(U[2].y) * wz + bfh(U[3].y) * ww;  \
      unsigned r0, r1;                                                                        \
      asm("v_cvt_pk_bf16_f32 %0, %1, %2" : "=v"(r0) : "v"(lo0), "v"(hi0));                    \
      asm("v_cvt_pk_bf16_f32 %0, %1, %2" : "=v"(r1) : "v"(lo1), "v"(hi1));                    \
      *(uint2*)(&SL[p * SLS + (kk) * 64 + ch]) = make_uint2(r0, r1);                          \
    }

#pragma unroll
    for (int ti = 0; ti < 2; ti++) {
      __hip_bfloat16* SL = (__hip_bfloat16*)(smem + ti * TS);
      int povt = pov[ti];
      float pwxt = pwx[ti], pwyt = pwy[ti], pwzt = pwz[ti], pwwt = pww[ti];
      LOADK(uA[0], 0) LOADK(uA[1], 1) LOADK(uA[2], 2)
      LOADK(uB[0], 3) LOADK(uB[1], 4)
      COMBK(uA[0], 0) COMBK(uA[1], 1) COMBK(uA[2], 2)
      LOADK(uC[0], 5) LOADK(uC[1], 6)
      COMBK(uB[0], 3) COMBK(uB[1], 4)
      LOADK(uD[0], 7) LOADK(uD[1], 8)
      COMBK(uC[0], 5) COMBK(uC[1], 6)
      COMBK(uD[0], 7) COMBK(uD[1], 8)
    }
#undef LOADK
#undef COMBK
  }
  __syncthreads();  // D: SL complete (both tiles)

  // phase 3: main GEMMs, both tiles — wave's 16 oc x 16 px, K=576; BN+ReLU
  {
    int r16 = lane & 15, quad = lane >> 4;
    floatx4 binit = *(const floatx4*)(bias2 + wave * 16 + quad * 4);
    const unsigned short* Ap = Wm + (wave * 16 + r16) * 576 + quad * 8;
#pragma unroll
    for (int ti = 0; ti < 2; ti++) {
      const __hip_bfloat16* SL = (const __hip_bfloat16*)(smem + ti * TS);
      const __hip_bfloat16* Sp = &SL[r16 * SLS + quad * 8];
      floatx4 acc0 = binit;
      floatx4 acc1 = {0.f, 0.f, 0.f, 0.f};
#pragma unroll
      for (int kc0 = 0; kc0 < 576; kc0 += 64) {
        short8 av0 = *(const short8*)(Ap + kc0);
        short8 bv0 = *(const short8*)(Sp + kc0);
        acc0 = __builtin_amdgcn_mfma_f32_16x16x32_bf16(av0, bv0, acc0, 0, 0, 0);
        short8 av1 = *(const short8*)(Ap + kc0 + 32);
        short8 bv1 = *(const short8*)(Sp + kc0 + 32);
        acc1 = __builtin_amdgcn_mfma_f32_16x16x32_bf16(av1, bv1, acc1, 0, 0, 0);
      }
      floatx4 acc = acc0 + acc1;
#pragma unroll
      for (int r = 0; r < 4; r++) {
        int o = wave * 16 + quad * 4 + r;
        out[((b * CO + o) * HH + h) * WW + w00 + ti * 16 + r16] = fmaxf(acc[r], 0.f);
      }
    }
  }
}

extern "C" void kernel_launch(void* const* d_in, const int* in_sizes, int n_in,
                              void* d_out, int out_size, void* d_ws, size_t ws_size,
                              hipStream_t stream) {
  const float* x = (const float*)d_in[0];
  const float* w_off = (const float*)d_in[1];
  const float* b_off = (const float*)d_in[2];
  const float* weight = (const float*)d_in[3];
  const float* bias = (const float*)d_in[4];
  const float* gamma = (const float*)d_in[5];
  const float* beta = (const float*)d_in[6];
  const float* run_mean = (const float*)d_in[7];
  const float* run_var = (const float*)d_in[8];
  float* outp = (float*)d_out;

  char* ws = (char*)d_ws;
  unsigned* xTb = (unsigned*)ws;                           // 4,194,304 B (bf16 NHWC)
  unsigned short* Wm = (unsigned short*)(ws + 4194304);    //    73,728 B
  unsigned short* w2 = (unsigned short*)(ws + 4268032);    //    36,864 B
  float* bias2 = (float*)(ws + 4304896);                   //       256 B
  float* boff2 = (float*)(ws + 4305152);                   //       128 B

  prep_kernel<<<1168, 256, 0, stream>>>(x, xTb, weight, bias, gamma, beta,
                                        run_mean, run_var, w_off, b_off,
                                        Wm, w2, bias2, boff2);
  dcn_kernel<<<1024, 256, 0, stream>>>((const unsigned short*)xTb, w2, boff2,
                                       Wm, bias2, outp);
}

// Round 11
// 108.916 us; speedup vs baseline: 1.0791x; 1.0157x over previous
//
#include <hip/hip_runtime.h>
#include <hip/hip_bf16.h>

#define HH 128
#define WW 128
#define CI 64
#define CO 64
#define SLS 584    // SL row stride in bf16 elems (576 + 8 pad)
#define HPS 72     // halo pixel stride in bf16 elems (64 + 8 pad, 144B = 9x16B)
#define HALW 18    // halo width: image cols w0-1 .. w0+16
#define TS 18688   // per-tile LDS region (bytes)

typedef __attribute__((ext_vector_type(8))) short short8;
typedef __attribute__((ext_vector_type(4))) float floatx4;

__device__ __forceinline__ unsigned short f2bf(float f) {
  union { float f; unsigned u; } uu; uu.f = f;
  unsigned r = uu.u + 0x7FFFu + ((uu.u >> 16) & 1u);  // RNE
  return (unsigned short)(r >> 16);
}
__device__ __forceinline__ unsigned pack2bf(float lo, float hi) {
  return (unsigned)f2bf(lo) | ((unsigned)f2bf(hi) << 16);
}
__device__ __forceinline__ float bfl(unsigned u) { return __uint_as_float(u << 16); }
__device__ __forceinline__ float bfh(unsigned u) { return __uint_as_float(u & 0xffff0000u); }

// ---- K1: blocks 0..1023 transcode x (f32 NCHW) -> xTb (bf16 NHWC ch-pairs),
//          32 px per block; blocks 1024..1167 prep Wm/w2/bias2/boff2 ----
__global__ __launch_bounds__(256) void prep_kernel(
    const float* __restrict__ x, unsigned* __restrict__ xTb_u,
    const float* __restrict__ weight, const float* __restrict__ bias,
    const float* __restrict__ gamma, const float* __restrict__ beta,
    const float* __restrict__ mean, const float* __restrict__ var,
    const float* __restrict__ w_off, const float* __restrict__ b_off,
    unsigned short* __restrict__ Wm, unsigned short* __restrict__ w2,
    float* __restrict__ bias2, float* __restrict__ boff2) {
  __shared__ unsigned T2[32 * 33];  // [px][cp] with +1 pad: 4,224 B
  int bid = blockIdx.x;
  int tid = threadIdx.x;
  if (bid < 1024) {
    int b = bid >> 9, h = (bid >> 2) & 127, q = bid & 3;  // 32-px chunk q
    int cp = tid >> 3, wc = tid & 7;  // ch pair (2cp,2cp+1), 4-px chunk wc
    const float* xp = x + (((long)(b * CI + 2 * cp) * HH + h) * WW + q * 32 + wc * 4);
    float4 a0 = *(const float4*)xp;              // ch 2cp
    float4 a1 = *(const float4*)(xp + HH * WW);  // ch 2cp+1
    T2[(wc * 4 + 0) * 33 + cp] = pack2bf(a0.x, a1.x);
    T2[(wc * 4 + 1) * 33 + cp] = pack2bf(a0.y, a1.y);
    T2[(wc * 4 + 2) * 33 + cp] = pack2bf(a0.z, a1.z);
    T2[(wc * 4 + 3) * 33 + cp] = pack2bf(a0.w, a1.w);
    __syncthreads();
    int px = tid >> 3, g = tid & 7;
    const unsigned* src = &T2[px * 33 + g * 4];
    unsigned* dst = xTb_u + ((long)((b * HH + h) * WW + q * 32 + px)) * 32 + g * 4;
    *(uint4*)dst = make_uint4(src[0], src[1], src[2], src[3]);
    return;
  }
  int idx = (bid - 1024) * 256 + tid;
  if (idx < 32) boff2[idx] = (idx < 27) ? b_off[idx] : 0.f;
  if (idx >= CO * 576) return;
  int o = idx / 576, kc = idx - o * 576;
  int k = kc >> 6, c = kc & 63;
  float inv = gamma[o] * rsqrtf(var[o] + 1e-5f);
  Wm[idx] = f2bf(weight[(o * CI + c) * 9 + k] * inv);
  if (kc == 0) bias2[o] = (bias[o] - mean[o]) * inv + beta[o];
  if (o < 27) w2[idx] = f2bf(w_off[o * 576 + c * 9 + k]);
  else if (o < 32) w2[idx] = 0;
}

// ---- K2: fused DCN, TWO 16-px tiles per block, 1024 blocks (4/CU, one
// generation). Every phase covers both tiles -> half the barriers per pixel.
// Per-tile LDS region (18,688 B): SL[16][584]; hal aliases rows 0-6;
// omL aliases rows 12-15. Total 37,376 B.
__global__ __launch_bounds__(256, 4) void dcn_kernel(
    const unsigned short* __restrict__ xTb,
    const unsigned short* __restrict__ w2, const float* __restrict__ boff2,
    const unsigned short* __restrict__ Wm, const float* __restrict__ bias2,
    float* __restrict__ out) {
  __shared__ char smem[2 * TS];

  int bid = blockIdx.x;
  int s = bid & 7;              // XCD slab key
  int n = bid >> 3;             // 0..127
  int b = n >> 6;
  int rem = n & 63;
  int h = s * 16 + (rem >> 2);
  int w00 = (rem & 3) * 32;     // tile X at w00, tile Y at w00+16
  int tid = threadIdx.x, lane = tid & 63, wave = tid >> 6;

  // phase 0: stage BOTH halos (864 tasks = 2 x 432), zeros off-image
#pragma unroll
  for (int it = 0; it < 4; it++) {
    int t = it * 256 + tid;
    if (t < 864) {
      int ti = (t >= 432);
      int tt = t - ti * 432;
      int row = tt / 144;
      int r2 = tt - row * 144;
      int xi = r2 >> 3, cg = r2 & 7;
      int y = h - 1 + row, xx = w00 + ti * 16 - 1 + xi;
      uint4 v = make_uint4(0u, 0u, 0u, 0u);
      if ((unsigned)y < (unsigned)HH && (unsigned)xx < (unsigned)WW)
        v = *(const uint4*)(xTb + (long)((b * HH + y) * WW + xx) * CI + cg * 8);
      short* hal = (short*)(smem + ti * TS);
      *(uint4*)(hal + (row * HALW + xi) * HPS + cg * 8) = v;
    }
  }
  __syncthreads();  // A: halos ready

  // phase 1: offset GEMMs, both tiles. wave=(m16,kh), M=32(27) N=16 K=576
  {
    int r16 = lane & 15, quad = lane >> 4;
    int m16 = wave & 1, kh = wave >> 1;
#pragma unroll
    for (int ti = 0; ti < 2; ti++) {
      short* hal = (short*)(smem + ti * TS);
      float* omL = (float*)(smem + ti * TS + 14016);
      floatx4 t0 = {0.f, 0.f, 0.f, 0.f};
      floatx4 t1 = {0.f, 0.f, 0.f, 0.f};
      if (kh == 0) t0 = *(const floatx4*)(boff2 + m16 * 16 + quad * 4);
      const short* ap = (const short*)(w2 + (m16 * 16 + r16) * 576 + kh * 32 + quad * 8);
#pragma unroll
      for (int kk = 0; kk < 9; kk++) {
        int dy = kk / 3, dxk = kk - 3 * dy;
        short8 bfrag = *(const short8*)(hal + (dy * HALW + r16 + dxk) * HPS + kh * 32 + quad * 8);
        short8 afrag = *(const short8*)(ap + kk * 64);
        if (kk & 1)
          t1 = __builtin_amdgcn_mfma_f32_16x16x32_bf16(afrag, bfrag, t1, 0, 0, 0);
        else
          t0 = __builtin_amdgcn_mfma_f32_16x16x32_bf16(afrag, bfrag, t0, 0, 0, 0);
      }
      floatx4 t = t0 + t1;
      // C layout: col=r16=px, row=quad*4+r=oc-in-tile
      *(floatx4*)(omL + kh * 576 + r16 * 36 + m16 * 16 + quad * 4) = t;
    }
  }
  __syncthreads();  // B: omL ready, hal reads done

  // phase 2a: params for both tiles, kept in REGISTERS
  float pwx[2] = {0.f, 0.f}, pwy[2] = {0.f, 0.f}, pwz[2] = {0.f, 0.f}, pww[2] = {0.f, 0.f};
  int pov[2] = {0, 0};
  if (lane < 36) {
    int p_loc = (lane * 7282) >> 16;  // lane/9
    int k = lane - p_loc * 9;
    int p = wave * 4 + p_loc;
    int ky = (k * 11) >> 5;  // k/3
    int kx = k - 3 * ky;
#pragma unroll
    for (int ti = 0; ti < 2; ti++) {
      const float* omL = (const float*)(smem + ti * TS + 14016);
      int w0 = w00 + ti * 16;
      const float* o0 = omL + p * 36;
      const float* o1 = omL + 576 + p * 36;
      float oy = o0[2 * k] + o1[2 * k];
      float ox = o0[2 * k + 1] + o1[2 * k + 1];
      float mm = o0[18 + k] + o1[18 + k];
      float msk = 1.f / (1.f + __expf(-mm));
      float py = (float)(h - 1 + ky) + oy;
      float pxx = (float)(w0 + p - 1 + kx) + ox;
      float y0f = floorf(py), x0f = floorf(pxx);
      float ly = py - y0f, lx = pxx - x0f;
      int y0 = (int)y0f, x0 = (int)x0f;
      int y1 = y0 + 1, x1 = x0 + 1;
      float lylx = ly * lx;
      bool y0v = (unsigned)y0 < (unsigned)HH, y1v = (unsigned)y1 < (unsigned)HH;
      bool x0v = (unsigned)x0 < (unsigned)WW, x1v = (unsigned)x1 < (unsigned)WW;
      int yc0 = min(max(y0, 0), HH - 1), yc1 = min(max(y1, 0), HH - 1);
      int xc0 = min(max(x0, 0), WW - 1), xc1 = min(max(x1, 0), WW - 1);
      pwx[ti] = (y0v && x0v) ? (1.f - ly - lx + lylx) * msk : 0.f;
      pwy[ti] = (y0v && x1v) ? (lx - lylx) * msk : 0.f;
      pwz[ti] = (y1v && x0v) ? (ly - lylx) * msk : 0.f;
      pww[ti] = (y1v && x1v) ? lylx * msk : 0.f;
      int off00 = (yc0 * WW + xc0) * CI;     // < 2^20
      int dxs = (xc1 - xc0) * CI;            // 0 or 64
      int dys = (yc1 - yc0) * WW * CI;       // 0 or 8192
      pov[ti] = off00 | ((dxs >> 6) << 20) | ((dys >> 13) << 21);
    }
  }
  __syncthreads();  // C: omL reads done before SL rows 12-15 are overwritten

  // phase 2b: gathers for both tiles; pov shfls PRE-HOISTED so the 36-load
  // cluster issues back-to-back (no ds_bpermute interleaved with the loads)
  {
    int cq = lane & 15, pl = lane >> 4;
    int p = wave * 4 + pl;
    int ch = cq * 4;
    const unsigned short* xb = xTb + (long)b * (HH * WW * CI);
    uint2 uA[3][4], uB[2][4], uC[2][4], uD[2][4];

#define LOADK(U, kk)                                  \
    {                                                 \
      int v = povr[kk];                               \
      int o00 = (v & 0xFFFFF) + ch;                   \
      int dxv = (v >> 14) & 64;                       \
      int dyv = (v >> 8) & 8192;                      \
      U[0] = *(const uint2*)(xb + o00);               \
      U[1] = *(const uint2*)(xb + o00 + dxv);         \
      U[2] = *(const uint2*)(xb + o00 + dyv);         \
      U[3] = *(const uint2*)(xb + o00 + dyv + dxv);   \
    }

#define COMBK(U, kk)                                                                          \
    {                                                                                         \
      int src = pl * 9 + (kk);                                                                \
      float wx = __shfl(pwxt, src), wy = __shfl(pwyt, src);                                   \
      float wz = __shfl(pwzt, src), ww = __shfl(pwwt, src);                                   \
      float lo0 = bfl(U[0].x) * wx + bfl(U[1].x) * wy + bfl(U[2].x) * wz + bfl(U[3].x) * ww;  \
      float hi0 = bfh(U[0].x) * wx + bfh(U[1].x) * wy + bfh(U[2].x) * wz + bfh(U[3].x) * ww;  \
      float lo1 = bfl(U[0].y) * wx + bfl(U[1].y) * wy + bfl(U[2].y) * wz + bfl(U[3].y) * ww;  \
      float hi1 = bfh(U[0].y) * wx + bfh(U[1].y) * wy + bfh(U[2].y) * wz + bfh(U[3].y) * ww;  \
      unsigned r0, r1;                                                                        \
      asm("v_cvt_pk_bf16_f32 %0, %1, %2" : "=v"(r0) : "v"(lo0), "v"(hi0));                    \
      asm("v_cvt_pk_bf16_f32 %0, %1, %2" : "=v"(r1) : "v"(lo1), "v"(hi1));                    \
      *(uint2*)(&SL[p * SLS + (kk) * 64 + ch]) = make_uint2(r0, r1);                          \
    }

#pragma unroll
    for (int ti = 0; ti < 2; ti++) {
      __hip_bfloat16* SL = (__hip_bfloat16*)(smem + ti * TS);
      float pwxt = pwx[ti], pwyt = pwy[ti], pwzt = pwz[ti], pwwt = pww[ti];
      int povr[9];
#pragma unroll
      for (int k = 0; k < 9; k++) povr[k] = __shfl(pov[ti], pl * 9 + k);
      LOADK(uA[0], 0) LOADK(uA[1], 1) LOADK(uA[2], 2)
      LOADK(uB[0], 3) LOADK(uB[1], 4)
      COMBK(uA[0], 0) COMBK(uA[1], 1) COMBK(uA[2], 2)
      LOADK(uC[0], 5) LOADK(uC[1], 6)
      COMBK(uB[0], 3) COMBK(uB[1], 4)
      LOADK(uD[0], 7) LOADK(uD[1], 8)
      COMBK(uC[0], 5) COMBK(uC[1], 6)
      COMBK(uD[0], 7) COMBK(uD[1], 8)
    }
#undef LOADK
#undef COMBK
  }
  __syncthreads();  // D: SL complete (both tiles)

  // phase 3: main GEMMs, both tiles — wave's 16 oc x 16 px, K=576; BN+ReLU
  {
    int r16 = lane & 15, quad = lane >> 4;
    floatx4 binit = *(const floatx4*)(bias2 + wave * 16 + quad * 4);
    const unsigned short* Ap = Wm + (wave * 16 + r16) * 576 + quad * 8;
#pragma unroll
    for (int ti = 0; ti < 2; ti++) {
      const __hip_bfloat16* SL = (const __hip_bfloat16*)(smem + ti * TS);
      const __hip_bfloat16* Sp = &SL[r16 * SLS + quad * 8];
      floatx4 acc0 = binit;
      floatx4 acc1 = {0.f, 0.f, 0.f, 0.f};
#pragma unroll
      for (int kc0 = 0; kc0 < 576; kc0 += 64) {
        short8 av0 = *(const short8*)(Ap + kc0);
        short8 bv0 = *(const short8*)(Sp + kc0);
        acc0 = __builtin_amdgcn_mfma_f32_16x16x32_bf16(av0, bv0, acc0, 0, 0, 0);
        short8 av1 = *(const short8*)(Ap + kc0 + 32);
        short8 bv1 = *(const short8*)(Sp + kc0 + 32);
        acc1 = __builtin_amdgcn_mfma_f32_16x16x32_bf16(av1, bv1, acc1, 0, 0, 0);
      }
      floatx4 acc = acc0 + acc1;
#pragma unroll
      for (int r = 0; r < 4; r++) {
        int o = wave * 16 + quad * 4 + r;
        out[((b * CO + o) * HH + h) * WW + w00 + ti * 16 + r16] = fmaxf(acc[r], 0.f);
      }
    }
  }
}

extern "C" void kernel_launch(void* const* d_in, const int* in_sizes, int n_in,
                              void* d_out, int out_size, void* d_ws, size_t ws_size,
                              hipStream_t stream) {
  const float* x = (const float*)d_in[0];
  const float* w_off = (const float*)d_in[1];
  const float* b_off = (const float*)d_in[2];
  const float* weight = (const float*)d_in[3];
  const float* bias = (const float*)d_in[4];
  const float* gamma = (const float*)d_in[5];
  const float* beta = (const float*)d_in[6];
  const float* run_mean = (const float*)d_in[7];
  const float* run_var = (const float*)d_in[8];
  float* outp = (float*)d_out;

  char* ws = (char*)d_ws;
  unsigned* xTb = (unsigned*)ws;                           // 4,194,304 B (bf16 NHWC)
  unsigned short* Wm = (unsigned short*)(ws + 4194304);    //    73,728 B
  unsigned short* w2 = (unsigned short*)(ws + 4268032);    //    36,864 B
  float* bias2 = (float*)(ws + 4304896);                   //       256 B
  float* boff2 = (float*)(ws + 4305152);                   //       128 B

  prep_kernel<<<1168, 256, 0, stream>>>(x, xTb, weight, bias, gamma, beta,
                                        run_mean, run_var, w_off, b_off,
                                        Wm, w2, bias2, boff2);
  dcn_kernel<<<1024, 256, 0, stream>>>((const unsigned short*)xTb, w2, boff2,
                                       Wm, bias2, outp);
}